// Round 10
// baseline (255.152 us; speedup 1.0000x reference)
//
#include <hip/hip_runtime.h>

// CenterLoss: out = mean_i sqrt( sum_d (x[i,d] - weight[targets[i],d])^2 + EPS )
// x: [N=65536, D=512] f32, weight: [C=1000, D=512] f32, targets: [N] i32.
//
// R10 = DIAGNOSTIC: 4 compute passes inside ONE dispatch (row mapping rotated
// per pass; each pass covers all rows; result scaled by inv_n/4 -> identical
// output). Purpose: the ~150us dispatch beats the harness's 78us fills into
// rocprof's top-5, giving us FETCH_SIZE / VALUBusy / Occupancy for OUR kernel.
// Fact base: 1 pass = 39us (R8), logical traffic 256 MB -> 6.56 TB/s = the
// machine's streaming ceiling. Hypothesis under test: w gather misses L2
// (thrashed by the x stream) and goes to HBM -> FETCH ~ 256 MB/pass.

typedef float f32x4 __attribute__((ext_vector_type(4)));

constexpr int D = 512;
constexpr float EPS = 1e-6f;
constexpr int RPW = 8;                 // rows per wave
constexpr int WPB = 4;                 // waves per block (256 threads)
constexpr int NPASS = 4;

__global__ __launch_bounds__(256) void centerloss_kernel(
    const float* __restrict__ x,
    const float* __restrict__ w,
    const int*   __restrict__ targets,
    float* __restrict__ out,
    int n_rows, float inv_n)
{
    const int lane = threadIdx.x & 63;
    const int wave = threadIdx.x >> 6;
    const int gw0 = blockIdx.x * WPB + wave;
    const int nWaves = gridDim.x * WPB;            // 8192

    float wsum = 0.0f;
    const f32x4 fz = {0.f, 0.f, 0.f, 0.f};

    for (int pass = 0; pass < NPASS; ++pass) {
        // Rotate wave->rows mapping each pass (bijective; covers all rows).
        const int gw = (gw0 + pass * (nWaves / NPASS)) & (nWaves - 1);
        const long base = (long)gw * RPW;

        // One-shot target prefetch: lane k (k<8) holds targets[base+k].
        int tml = 0;
        {
            const long r = base + lane;
            if (lane < RPW && r < (long)n_rows) tml = targets[r];
        }

        #pragma unroll
        for (int k = 0; k < RPW; k += 2) {
            const long r0 = base + k;
            const long r1 = base + k + 1;
            const bool v0 = r0 < (long)n_rows;
            const bool v1 = r1 < (long)n_rows;
            const int t0 = __builtin_amdgcn_readlane(tml, k);
            const int t1 = __builtin_amdgcn_readlane(tml, k + 1);

            const f32x4* __restrict__ xr0 = reinterpret_cast<const f32x4*>(x + r0 * D);
            const f32x4* __restrict__ xr1 = reinterpret_cast<const f32x4*>(x + r1 * D);
            const f32x4* __restrict__ wr0 = reinterpret_cast<const f32x4*>(w + (size_t)t0 * D);
            const f32x4* __restrict__ wr1 = reinterpret_cast<const f32x4*>(w + (size_t)t1 * D);

            f32x4 xa0 = fz, xb0 = fz, wa0 = fz, wb0 = fz;
            f32x4 xa1 = fz, xb1 = fz, wa1 = fz, wb1 = fz;
            if (v0) {
                xa0 = __builtin_nontemporal_load(&xr0[lane]);
                xb0 = __builtin_nontemporal_load(&xr0[lane + 64]);
                wa0 = wr0[lane];
                wb0 = wr0[lane + 64];
            }
            if (v1) {
                xa1 = __builtin_nontemporal_load(&xr1[lane]);
                xb1 = __builtin_nontemporal_load(&xr1[lane + 64]);
                wa1 = wr1[lane];
                wb1 = wr1[lane + 64];
            }

            float a0 = 0.f, a1 = 0.f, d;
            d = xa0.x - wa0.x; a0 = fmaf(d, d, a0);
            d = xa0.y - wa0.y; a0 = fmaf(d, d, a0);
            d = xa0.z - wa0.z; a0 = fmaf(d, d, a0);
            d = xa0.w - wa0.w; a0 = fmaf(d, d, a0);
            d = xb0.x - wb0.x; a0 = fmaf(d, d, a0);
            d = xb0.y - wb0.y; a0 = fmaf(d, d, a0);
            d = xb0.z - wb0.z; a0 = fmaf(d, d, a0);
            d = xb0.w - wb0.w; a0 = fmaf(d, d, a0);

            d = xa1.x - wa1.x; a1 = fmaf(d, d, a1);
            d = xa1.y - wa1.y; a1 = fmaf(d, d, a1);
            d = xa1.z - wa1.z; a1 = fmaf(d, d, a1);
            d = xa1.w - wa1.w; a1 = fmaf(d, d, a1);
            d = xb1.x - wb1.x; a1 = fmaf(d, d, a1);
            d = xb1.y - wb1.y; a1 = fmaf(d, d, a1);
            d = xb1.z - wb1.z; a1 = fmaf(d, d, a1);
            d = xb1.w - wb1.w; a1 = fmaf(d, d, a1);

            #pragma unroll
            for (int off = 1; off < 64; off <<= 1) {
                a0 += __shfl_xor(a0, off, 64);
                a1 += __shfl_xor(a1, off, 64);
            }
            if (v0) wsum += sqrtf(a0 + EPS);
            if (v1) wsum += sqrtf(a1 + EPS);
        }
    }

    __shared__ float smem[WPB];
    if (lane == 0) smem[wave] = wsum;
    __syncthreads();

    if (threadIdx.x == 0) {
        float s = 0.0f;
        #pragma unroll
        for (int i = 0; i < WPB; ++i) s += smem[i];
        atomicAdd(out, s * inv_n);      // inv_n pre-divided by NPASS
    }
}

extern "C" void kernel_launch(void* const* d_in, const int* in_sizes, int n_in,
                              void* d_out, int out_size, void* d_ws, size_t ws_size,
                              hipStream_t stream) {
    const float* x       = (const float*)d_in[0];
    const float* weight  = (const float*)d_in[1];
    const int*   targets = (const int*)d_in[2];
    float* out = (float*)d_out;

    const int n_rows = in_sizes[2];   // 65536

    // d_out is poisoned to 0xAA before every call; zero it for the atomicAdd.
    (void)hipMemsetAsync(d_out, 0, sizeof(float), stream);

    const int rowsPerBlock = WPB * RPW;                 // 32
    const int grid = (n_rows + rowsPerBlock - 1) / rowsPerBlock;  // 2048
    centerloss_kernel<<<grid, 256, 0, stream>>>(x, weight, targets, out,
                                                n_rows,
                                                1.0f / ((float)n_rows * NPASS));
}

// Round 11
// 213.815 us; speedup vs baseline: 1.1933x; 1.1933x over previous
//
#include <hip/hip_runtime.h>

// CenterLoss: out = mean_i sqrt( sum_d (x[i,d] - weight[targets[i],d])^2 + EPS )
// x: [N=65536, D=512] f32, weight: [C=1000, D=512] f32, targets: [N] i32.
//
// R11: 16-lane-per-row layout. R10 counters (4-pass diag): HBM 31%, VALU 27%,
// Occ 53%, FETCH shows w is cache-resident — nothing saturated, so the gap
// (39us vs ~20us ideal) is in-kernel serial overhead. Main suspect: the
// 6-stage 64-lane shuffle butterfly per row (12 dependent DS ops / 2 rows,
// ~1500 DS ops per CU per pass through the single DS pipe). This version
// reduces within 16-lane groups (4 rows per wave concurrently): 4-stage
// butterfly carrying 4 rows at once -> DS ops per wave ~150 -> ~22.

typedef float f32x4 __attribute__((ext_vector_type(4)));

constexpr int D = 512;
constexpr float EPS = 1e-6f;
constexpr int RPW = 8;                 // rows per wave (2 steps x 4 rows)
constexpr int WPB = 4;                 // waves per block (256 threads)

__global__ __launch_bounds__(256) void centerloss_kernel(
    const float* __restrict__ x,
    const float* __restrict__ w,
    const int*   __restrict__ targets,
    float* __restrict__ out,
    int n_rows, float inv_16n)
{
    const int lane = threadIdx.x & 63;
    const int wave = threadIdx.x >> 6;
    const int grp  = lane >> 4;        // 0..3: which of 4 concurrent rows
    const int sub  = lane & 15;        // 0..15: position within the row
    const int gw = blockIdx.x * WPB + wave;
    const long base = (long)gw * RPW;

    // Prefetch this wave's 8 targets: lane k (k<8) holds targets[base+k].
    int tml = 0;
    if (lane < RPW) {
        const long r = base + lane;
        if (r < (long)n_rows) tml = targets[r];
    }

    float wsum = 0.0f;
    const bool fast = (base + RPW) <= (long)n_rows;   // block fully in range

    #pragma unroll
    for (int step = 0; step < 2; ++step) {
        const long r = base + step * 4 + grp;          // this group's row
        const int  t = __shfl(tml, step * 4 + grp, 64); // group's target (1 DS op)
        const bool v = fast || (r < (long)n_rows);

        float a = 0.0f;
        if (v) {
            const f32x4* __restrict__ xr =
                reinterpret_cast<const f32x4*>(x + r * D);
            const f32x4* __restrict__ wr =
                reinterpret_cast<const f32x4*>(w + (size_t)t * D);
            // Row = 128 float4; 16 lanes x 8 float4 each. Each wave-instr
            // covers 4 rows x 256 B contiguous -> fully coalesced.
            #pragma unroll
            for (int j = 0; j < 8; ++j) {
                const f32x4 xv = xr[sub + j * 16];
                const f32x4 wv = wr[sub + j * 16];
                float d;
                d = xv.x - wv.x; a = fmaf(d, d, a);
                d = xv.y - wv.y; a = fmaf(d, d, a);
                d = xv.z - wv.z; a = fmaf(d, d, a);
                d = xv.w - wv.w; a = fmaf(d, d, a);
            }
        }

        // 4-stage xor butterfly within each 16-lane group (4 rows at once).
        #pragma unroll
        for (int off = 1; off < 16; off <<= 1)
            a += __shfl_xor(a, off, 64);

        // All 16 lanes of the group now hold the row's ssq (16x overcount,
        // folded into inv_16n on the host).
        if (v) wsum += sqrtf(a + EPS);
    }

    // Reduce wsum across the full wave (6 DS ops, once per kernel).
    #pragma unroll
    for (int off = 1; off < 64; off <<= 1)
        wsum += __shfl_xor(wsum, off, 64);

    __shared__ float smem[WPB];
    if (lane == 0) smem[wave] = wsum;
    __syncthreads();

    if (threadIdx.x == 0) {
        float s = 0.0f;
        #pragma unroll
        for (int i = 0; i < WPB; ++i) s += smem[i];
        atomicAdd(out, s * inv_16n);   // inv_16n = 1/(16*N): mean + overcount
    }
}

extern "C" void kernel_launch(void* const* d_in, const int* in_sizes, int n_in,
                              void* d_out, int out_size, void* d_ws, size_t ws_size,
                              hipStream_t stream) {
    const float* x       = (const float*)d_in[0];
    const float* weight  = (const float*)d_in[1];
    const int*   targets = (const int*)d_in[2];
    float* out = (float*)d_out;

    const int n_rows = in_sizes[2];   // 65536

    // d_out is poisoned to 0xAA before every call; zero it for the atomicAdd.
    (void)hipMemsetAsync(d_out, 0, sizeof(float), stream);

    const int rowsPerBlock = WPB * RPW;                 // 32
    const int grid = (n_rows + rowsPerBlock - 1) / rowsPerBlock;  // 2048
    centerloss_kernel<<<grid, 256, 0, stream>>>(x, weight, targets, out,
                                                n_rows,
                                                1.0f / (16.0f * (float)n_rows));
}

// Round 12
// 201.126 us; speedup vs baseline: 1.2686x; 1.0631x over previous
//
#include <hip/hip_runtime.h>

// CenterLoss: out = mean_i sqrt( sum_d (x[i,d] - weight[targets[i],d])^2 + EPS )
// x: [N=65536, D=512] f32, weight: [C=1000, D=512] f32, targets: [N] i32.
//
// R12 = REVERT to best-measured kernel (R9, 199.87us). R11's 16-lane layout
// regressed (-14us: 4x256B segments per wave-load vs 1x1KB).
//
// Roofline assessment (R8+R10 evidence): one cold pass = 39us = 128 MB
// compulsory x-read at 3.28 TB/s, matching the device's demonstrated pure-
// read ceiling (m13 copy read component ~3.15 TB/s; fills at 6.8 TB/s are
// write-only). FETCH_SIZE shows zero over-fetch; TA path demonstrated
// 20 B/cyc/CU on warm passes (not the limiter); VALU 27%, LDS conflicts 0.
// Removing w traffic (R7), XCD swizzle (R9), ILP (R5) all null -> the
// kernel is at the cold-read HBM roofline. Residual dur_us ~160us is
// harness reset traffic (512 MB ws poison + input restore).

typedef float f32x4 __attribute__((ext_vector_type(4)));

constexpr int D = 512;
constexpr float EPS = 1e-6f;
constexpr int RPW = 8;                 // rows per wave
constexpr int WPB = 4;                 // waves per block (256 threads)

__global__ __launch_bounds__(256) void centerloss_kernel(
    const float* __restrict__ x,
    const float* __restrict__ w,
    const int*   __restrict__ targets,
    float* __restrict__ out,
    int n_rows, float inv_n)
{
    const int lane = threadIdx.x & 63;
    const int wave = threadIdx.x >> 6;

    // XCD-aware bijective swizzle (measured null, kept from best-measured run).
    const int bid = blockIdx.x;
    const int chunk = gridDim.x >> 3;              // 2048/8 = 256
    const int wg = (bid & 7) * chunk + (bid >> 3);

    const int gw = wg * WPB + wave;
    const long base = (long)gw * RPW;

    // One-shot target prefetch: lane k (k<8) holds targets[base+k].
    int tml = 0;
    {
        const long r = base + lane;
        if (lane < RPW && r < (long)n_rows) tml = targets[r];
    }

    float wsum = 0.0f;
    const f32x4 fz = {0.f, 0.f, 0.f, 0.f};

    #pragma unroll
    for (int k = 0; k < RPW; k += 2) {
        const long r0 = base + k;
        const long r1 = base + k + 1;
        const bool v0 = r0 < (long)n_rows;       // wave-uniform guards
        const bool v1 = r1 < (long)n_rows;
        const int t0 = __builtin_amdgcn_readlane(tml, k);
        const int t1 = __builtin_amdgcn_readlane(tml, k + 1);

        const f32x4* __restrict__ xr0 = reinterpret_cast<const f32x4*>(x + r0 * D);
        const f32x4* __restrict__ xr1 = reinterpret_cast<const f32x4*>(x + r1 * D);
        const f32x4* __restrict__ wr0 = reinterpret_cast<const f32x4*>(w + (size_t)t0 * D);
        const f32x4* __restrict__ wr1 = reinterpret_cast<const f32x4*>(w + (size_t)t1 * D);

        f32x4 xa0 = fz, xb0 = fz, wa0 = fz, wb0 = fz;
        f32x4 xa1 = fz, xb1 = fz, wa1 = fz, wb1 = fz;
        if (v0) {
            xa0 = __builtin_nontemporal_load(&xr0[lane]);
            xb0 = __builtin_nontemporal_load(&xr0[lane + 64]);
            wa0 = wr0[lane];
            wb0 = wr0[lane + 64];
        }
        if (v1) {
            xa1 = __builtin_nontemporal_load(&xr1[lane]);
            xb1 = __builtin_nontemporal_load(&xr1[lane + 64]);
            wa1 = wr1[lane];
            wb1 = wr1[lane + 64];
        }

        float a0 = 0.f, a1 = 0.f, d;
        d = xa0.x - wa0.x; a0 = fmaf(d, d, a0);
        d = xa0.y - wa0.y; a0 = fmaf(d, d, a0);
        d = xa0.z - wa0.z; a0 = fmaf(d, d, a0);
        d = xa0.w - wa0.w; a0 = fmaf(d, d, a0);
        d = xb0.x - wb0.x; a0 = fmaf(d, d, a0);
        d = xb0.y - wb0.y; a0 = fmaf(d, d, a0);
        d = xb0.z - wb0.z; a0 = fmaf(d, d, a0);
        d = xb0.w - wb0.w; a0 = fmaf(d, d, a0);

        d = xa1.x - wa1.x; a1 = fmaf(d, d, a1);
        d = xa1.y - wa1.y; a1 = fmaf(d, d, a1);
        d = xa1.z - wa1.z; a1 = fmaf(d, d, a1);
        d = xa1.w - wa1.w; a1 = fmaf(d, d, a1);
        d = xb1.x - wb1.x; a1 = fmaf(d, d, a1);
        d = xb1.y - wb1.y; a1 = fmaf(d, d, a1);
        d = xb1.z - wb1.z; a1 = fmaf(d, d, a1);
        d = xb1.w - wb1.w; a1 = fmaf(d, d, a1);

        #pragma unroll
        for (int off = 1; off < 64; off <<= 1) {
            a0 += __shfl_xor(a0, off, 64);
            a1 += __shfl_xor(a1, off, 64);
        }
        if (v0) wsum += sqrtf(a0 + EPS);
        if (v1) wsum += sqrtf(a1 + EPS);
    }

    __shared__ float smem[WPB];
    if (lane == 0) smem[wave] = wsum;
    __syncthreads();

    if (threadIdx.x == 0) {
        float s = 0.0f;
        #pragma unroll
        for (int i = 0; i < WPB; ++i) s += smem[i];
        atomicAdd(out, s * inv_n);      // pre-scaled: out = mean
    }
}

extern "C" void kernel_launch(void* const* d_in, const int* in_sizes, int n_in,
                              void* d_out, int out_size, void* d_ws, size_t ws_size,
                              hipStream_t stream) {
    const float* x       = (const float*)d_in[0];
    const float* weight  = (const float*)d_in[1];
    const int*   targets = (const int*)d_in[2];
    float* out = (float*)d_out;

    const int n_rows = in_sizes[2];   // 65536

    // d_out is poisoned to 0xAA before every call; zero it for the atomicAdd.
    (void)hipMemsetAsync(d_out, 0, sizeof(float), stream);

    const int rowsPerBlock = WPB * RPW;                 // 32
    const int grid = (n_rows + rowsPerBlock - 1) / rowsPerBlock;  // 2048
    centerloss_kernel<<<grid, 256, 0, stream>>>(x, weight, targets, out,
                                                n_rows, 1.0f / (float)n_rows);
}